// Round 1
// baseline (92.609 us; speedup 1.0000x reference)
//
#include <hip/hip_runtime.h>
#include <math.h>

#define TILE 2048
#define RSPLIT 4

__device__ __forceinline__ float decode_scalar(const int* p) {
    int i = *p;
    // Python int scalar -> int32; if it were float32, bits of small floats are huge ints.
    if (i > -16777216 && i < 16777216) return (float)i;
    return __int_as_float(i);
}

// Stage 1: partial nearest-neighbor min over a chunk of the reference set.
// dir 0: query=preds (Q=M), ref=gts (R=N)  -> contributes to loss_1
// dir 1: query=gts  (Q=N), ref=preds(R=M)  -> contributes to loss_2
// Tracks min over (||r||^2 - 2<q,r>); adds ||q||^2 at the end (commutes with min).
__global__ __launch_bounds__(256) void nn_partial_min(
    const float* __restrict__ preds, const float* __restrict__ gts,
    int M, int N, int B, int Qmax, float* __restrict__ ws)
{
    const int zc    = blockIdx.z;
    const int dir   = zc / RSPLIT;
    const int chunk = zc % RSPLIT;
    const int b     = blockIdx.y;

    const float* __restrict__ q = (dir == 0) ? preds : gts;
    const float* __restrict__ r = (dir == 0) ? gts   : preds;
    const int Q = (dir == 0) ? M : N;
    const int R = (dir == 0) ? N : M;

    const float* qb = q + (size_t)b * Q * 3;
    const float* rb = r + (size_t)b * R * 3;

    const int j = blockIdx.x * blockDim.x + threadIdx.x;
    float px = 0.f, py = 0.f, pz = 0.f;
    if (j < Q) { px = qb[3*j]; py = qb[3*j+1]; pz = qb[3*j+2]; }
    const float qn = px*px + py*py + pz*pz;

    __shared__ float4 pts[TILE];

    const int chunkLen = (R + RSPLIT - 1) / RSPLIT;
    const int start = chunk * chunkLen;
    const int end   = min(R, start + chunkLen);

    float best = INFINITY; // min of (rn - 2*dot)
    for (int t0 = start; t0 < end; t0 += TILE) {
        const int tl = min(TILE, end - t0);
        __syncthreads();
        for (int p = threadIdx.x; p < tl; p += blockDim.x) {
            const float x = rb[3*(t0+p)+0];
            const float y = rb[3*(t0+p)+1];
            const float z = rb[3*(t0+p)+2];
            pts[p] = make_float4(x, y, z, x*x + y*y + z*z);
        }
        __syncthreads();

        int i = 0;
        for (; i + 8 <= tl; i += 8) {
            #pragma unroll
            for (int u = 0; u < 8; u += 4) {
                const float4 p0 = pts[i+u+0];
                const float4 p1 = pts[i+u+1];
                const float4 p2 = pts[i+u+2];
                const float4 p3 = pts[i+u+3];
                const float d0 = fmaf(-2.f, fmaf(pz, p0.z, fmaf(py, p0.y, px*p0.x)), p0.w);
                const float d1 = fmaf(-2.f, fmaf(pz, p1.z, fmaf(py, p1.y, px*p1.x)), p1.w);
                const float d2 = fmaf(-2.f, fmaf(pz, p2.z, fmaf(py, p2.y, px*p2.x)), p2.w);
                const float d3 = fmaf(-2.f, fmaf(pz, p3.z, fmaf(py, p3.y, px*p3.x)), p3.w);
                best = fminf(best, fminf(fminf(d0, d1), fminf(d2, d3)));
            }
        }
        for (; i < tl; ++i) {
            const float4 p0 = pts[i];
            const float d0 = fmaf(-2.f, fmaf(pz, p0.z, fmaf(py, p0.y, px*p0.x)), p0.w);
            best = fminf(best, d0);
        }
    }

    const float v = best + qn;
    if (j < Qmax) {
        const size_t idx = (((size_t)dir * B + b) * RSPLIT + chunk) * (size_t)Qmax + j;
        ws[idx] = (j < Q) ? v : INFINITY;
    }
}

// Stage 2: combine RSPLIT partial mins, apply Huber, block/wave reduce, atomicAdd.
__global__ __launch_bounds__(256) void huber_reduce(
    const float* __restrict__ ws, const int* __restrict__ cptr,
    int M, int N, int B, int Qmax, float* __restrict__ out)
{
    const int dir = blockIdx.z;
    const int b   = blockIdx.y;
    const int Q   = (dir == 0) ? M : N;
    const int j   = blockIdx.x * blockDim.x + threadIdx.x;

    float h = 0.f;
    if (j < Q) {
        const size_t base = (((size_t)dir * B + b) * RSPLIT) * (size_t)Qmax + j;
        float v = ws[base];
        #pragma unroll
        for (int k = 1; k < RSPLIT; ++k) v = fminf(v, ws[base + (size_t)k * Qmax]);
        const float c = decode_scalar(cptr);
        h = (v < c) ? (0.5f * v * v) : (c * v - 0.5f * c * c);
    }

    #pragma unroll
    for (int off = 32; off > 0; off >>= 1) h += __shfl_down(h, off, 64);
    if ((threadIdx.x & 63) == 0) atomicAdd(out, h);
}

extern "C" void kernel_launch(void* const* d_in, const int* in_sizes, int n_in,
                              void* d_out, int out_size, void* d_ws, size_t ws_size,
                              hipStream_t stream) {
    const float* preds = (const float*)d_in[0];
    const float* gts   = (const float*)d_in[1];
    const int*   cptr  = (const int*)d_in[2];

    const int B = 4, D = 3;
    const int M = in_sizes[0] / (B * D); // preds count per batch
    const int N = in_sizes[1] / (B * D); // gts count per batch
    const int Qmax = (M > N) ? M : N;

    float* ws  = (float*)d_ws;
    float* out = (float*)d_out;

    hipMemsetAsync(d_out, 0, (size_t)out_size * sizeof(float), stream);

    dim3 g1((Qmax + 255) / 256, B, 2 * RSPLIT);
    nn_partial_min<<<g1, 256, 0, stream>>>(preds, gts, M, N, B, Qmax, ws);

    dim3 g2((Qmax + 255) / 256, B, 2);
    huber_reduce<<<g2, 256, 0, stream>>>(ws, cptr, M, N, B, Qmax, out);
}

// Round 2
// 73.713 us; speedup vs baseline: 1.2563x; 1.2563x over previous
//
#include <hip/hip_runtime.h>
#include <math.h>

#define TPTS 1024  // LDS tile: 1024 points * 16B = 16 KB

__device__ __forceinline__ float decode_scalar(const int* p) {
    int i = *p;
    if (i > -16777216 && i < 16777216) return (float)i;
    return __int_as_float(i);
}

// Prep: pack points as {2x, 2y, 2z, ||r||^2} so the pair distance collapses to
// 3 FMAs: d = fma(-qx, 2rx, fma(-qy, 2ry, fma(-qz, 2rz, rn)))  (+ qn after min)
__global__ __launch_bounds__(256) void pack_pts(
    const float* __restrict__ preds, const float* __restrict__ gts,
    int nP, int nG, float4* __restrict__ dst)
{
    const int which = blockIdx.y;
    const float* __restrict__ src = which ? gts : preds;
    const int n = which ? nG : nP;
    float4* __restrict__ d = dst + (which ? nP : 0);
    const int i = blockIdx.x * blockDim.x + threadIdx.x;
    if (i < n) {
        const float x = src[3*i], y = src[3*i+1], z = src[3*i+2];
        d[i] = make_float4(2.f*x, 2.f*y, 2.f*z, x*x + y*y + z*z);
    }
}

// Stage 1: partial NN min over a chunk of the ref set. 2 queries per lane so
// each broadcast LDS read amortizes over 2 pairs (VALU-bound, not LDS-bound).
__global__ __launch_bounds__(256) void nn_partial_min(
    const float4* __restrict__ packed, int M, int N, int B, int rsplit,
    int Qmax, float* __restrict__ part)
{
    const int zc    = blockIdx.z;
    const int dir   = zc / rsplit;
    const int chunk = zc - dir * rsplit;
    const int b     = blockIdx.y;

    const int Q = dir ? N : M;
    const int R = dir ? M : N;
    const size_t qbase = dir ? ((size_t)B*M + (size_t)b*N) : ((size_t)b*M);
    const size_t rbase = dir ? ((size_t)b*M)               : ((size_t)B*M + (size_t)b*N);

    const int tid = threadIdx.x;
    const int Qh  = (Q + 1) >> 1;
    const int j0  = blockIdx.x * 256 + tid;
    const int j1  = j0 + Qh;

    float nqx0=0.f, nqy0=0.f, nqz0=0.f, qn0=0.f;
    float nqx1=0.f, nqy1=0.f, nqz1=0.f, qn1=0.f;
    if (j0 < Q) {
        const float4 qp = packed[qbase + j0];
        nqx0 = -0.5f*qp.x; nqy0 = -0.5f*qp.y; nqz0 = -0.5f*qp.z; qn0 = qp.w;
    }
    if (j1 < Q) {
        const float4 qp = packed[qbase + j1];
        nqx1 = -0.5f*qp.x; nqy1 = -0.5f*qp.y; nqz1 = -0.5f*qp.z; qn1 = qp.w;
    }

    __shared__ float4 sh[TPTS];

    const int chunkLen = (R + rsplit - 1) / rsplit;
    const int start = chunk * chunkLen;
    const int end   = min(R, start + chunkLen);

    float best0 = INFINITY, best1 = INFINITY;
    for (int t0 = start; t0 < end; t0 += TPTS) {
        const int tl = min(TPTS, end - t0);
        __syncthreads();
        for (int p = tid; p < tl; p += 256) sh[p] = packed[rbase + t0 + p];
        __syncthreads();

        int i = 0;
        for (; i + 8 <= tl; i += 8) {
            float a0[8], a1[8];
            #pragma unroll
            for (int u = 0; u < 8; ++u) {
                const float4 r = sh[i + u];
                a0[u] = fmaf(nqx0, r.x, fmaf(nqy0, r.y, fmaf(nqz0, r.z, r.w)));
                a1[u] = fmaf(nqx1, r.x, fmaf(nqy1, r.y, fmaf(nqz1, r.z, r.w)));
            }
            // min-trees shaped for v_min3_f32 fusion
            best0 = fminf(best0, fminf(fminf(fminf(a0[0],a0[1]), fminf(a0[2],a0[3])),
                                       fminf(fminf(a0[4],a0[5]), fminf(a0[6],a0[7]))));
            best1 = fminf(best1, fminf(fminf(fminf(a1[0],a1[1]), fminf(a1[2],a1[3])),
                                       fminf(fminf(a1[4],a1[5]), fminf(a1[6],a1[7]))));
        }
        for (; i < tl; ++i) {
            const float4 r = sh[i];
            best0 = fminf(best0, fmaf(nqx0, r.x, fmaf(nqy0, r.y, fmaf(nqz0, r.z, r.w))));
            best1 = fminf(best1, fmaf(nqx1, r.x, fmaf(nqy1, r.y, fmaf(nqz1, r.z, r.w))));
        }
    }

    const size_t base = (((size_t)dir * B + b) * rsplit + chunk) * (size_t)Qmax;
    if (j0 < Qmax) part[base + j0] = (j0 < Q) ? best0 + qn0 : INFINITY;
    if (j1 < Qmax && j1 >= Qh) part[base + j1] = (j1 < Q) ? best1 + qn1 : INFINITY;
}

// Stage 2: combine rsplit partial mins, Huber, wave reduce, atomicAdd.
__global__ __launch_bounds__(256) void huber_reduce(
    const float* __restrict__ part, const int* __restrict__ cptr,
    int M, int N, int B, int rsplit, int Qmax, float* __restrict__ out)
{
    const int dir = blockIdx.z;
    const int b   = blockIdx.y;
    const int Q   = dir ? N : M;
    const int j   = blockIdx.x * blockDim.x + threadIdx.x;

    float h = 0.f;
    if (j < Q) {
        const size_t base = (((size_t)dir * B + b) * rsplit) * (size_t)Qmax + j;
        float v = part[base];
        for (int k = 1; k < rsplit; ++k) v = fminf(v, part[base + (size_t)k * Qmax]);
        const float c = decode_scalar(cptr);
        h = (v < c) ? (0.5f * v * v) : (c * v - 0.5f * c * c);
    }

    #pragma unroll
    for (int off = 32; off > 0; off >>= 1) h += __shfl_down(h, off, 64);
    if ((threadIdx.x & 63) == 0) atomicAdd(out, h);
}

extern "C" void kernel_launch(void* const* d_in, const int* in_sizes, int n_in,
                              void* d_out, int out_size, void* d_ws, size_t ws_size,
                              hipStream_t stream) {
    const float* preds = (const float*)d_in[0];
    const float* gts   = (const float*)d_in[1];
    const int*   cptr  = (const int*)d_in[2];

    const int B = 4, D = 3;
    const int M = in_sizes[0] / (B * D);
    const int N = in_sizes[1] / (B * D);
    const int Qmax = (M > N) ? M : N;
    const int nP = B * M, nG = B * N;

    const size_t packedBytes = ((size_t)nP + (size_t)nG) * sizeof(float4);
    int rsplit = 8;
    while (rsplit > 1 &&
           packedBytes + 2ull * B * rsplit * (size_t)Qmax * sizeof(float) > ws_size)
        rsplit >>= 1;

    float4* packed = (float4*)d_ws;
    float*  part   = (float*)((char*)d_ws + packedBytes);
    float*  out    = (float*)d_out;

    hipMemsetAsync(d_out, 0, (size_t)out_size * sizeof(float), stream);

    dim3 g0((max(nP, nG) + 255) / 256, 2, 1);
    pack_pts<<<g0, 256, 0, stream>>>(preds, gts, nP, nG, packed);

    dim3 g1((((Qmax + 1) / 2) + 255) / 256, B, 2 * rsplit);
    nn_partial_min<<<g1, 256, 0, stream>>>(packed, M, N, B, rsplit, Qmax, part);

    dim3 g2((Qmax + 255) / 256, B, 2);
    huber_reduce<<<g2, 256, 0, stream>>>(part, cptr, M, N, B, rsplit, Qmax, out);
}

// Round 3
// 69.976 us; speedup vs baseline: 1.3234x; 1.0534x over previous
//
#include <hip/hip_runtime.h>
#include <math.h>

#define TPTS 512  // LDS tile: 512 points * 16B = 8 KB

typedef float f32x2 __attribute__((ext_vector_type(2)));

__device__ __forceinline__ float decode_scalar(const int* p) {
    int i = *p;
    if (i > -16777216 && i < 16777216) return (float)i;
    return __int_as_float(i);
}

// d01 = {dist(q0,r), dist(q1,r)} accumulation via packed fp32 FMA.
// Refs packed {2x,2y,2z,rn}; queries hold -q. op_sel broadcasts one 32-bit
// half of the ref pair to both result lanes.
__device__ __forceinline__ f32x2 pk_fma_bcast_lo(f32x2 q, f32x2 p, f32x2 acc) {
    f32x2 d;  // both lanes use p.lo
    asm("v_pk_fma_f32 %0, %1, %2, %3 op_sel:[0,0,0] op_sel_hi:[1,0,1]"
        : "=v"(d) : "v"(q), "v"(p), "v"(acc));
    return d;
}
__device__ __forceinline__ f32x2 pk_fma_bcast_hi(f32x2 q, f32x2 p, f32x2 acc) {
    f32x2 d;  // both lanes use p.hi
    asm("v_pk_fma_f32 %0, %1, %2, %3 op_sel:[0,1,0] op_sel_hi:[1,1,1]"
        : "=v"(d) : "v"(q), "v"(p), "v"(acc));
    return d;
}
__device__ __forceinline__ f32x2 pk_fma_zinit(f32x2 q, f32x2 p1) {
    f32x2 d;  // d = q * p1.lo + p1.hi (both lanes)
    asm("v_pk_fma_f32 %0, %1, %2, %3 op_sel:[0,0,1] op_sel_hi:[1,0,1]"
        : "=v"(d) : "v"(q), "v"(p1), "v"(p1));
    return d;
}
__device__ __forceinline__ float min3f(float a, float b, float c) {
    float d;
    asm("v_min3_f32 %0, %1, %2, %3" : "=v"(d) : "v"(a), "v"(b), "v"(c));
    return d;
}

// Prep: pack points as {2x, 2y, 2z, ||r||^2}
__global__ __launch_bounds__(256) void pack_pts(
    const float* __restrict__ preds, const float* __restrict__ gts,
    int nP, int nG, float4* __restrict__ dst)
{
    const int which = blockIdx.y;
    const float* __restrict__ src = which ? gts : preds;
    const int n = which ? nG : nP;
    float4* __restrict__ d = dst + (which ? nP : 0);
    const int i = blockIdx.x * blockDim.x + threadIdx.x;
    if (i < n) {
        const float x = src[3*i], y = src[3*i+1], z = src[3*i+2];
        d[i] = make_float4(2.f*x, 2.f*y, 2.f*z, x*x + y*y + z*z);
    }
}

// Stage 1: partial NN min. 4 queries per lane, packed 2x2 into f32x2 pairs;
// 2 pk_fma-chains + min3 => 2.0 VALU instr per pair.
__global__ __launch_bounds__(256) void nn_partial_min(
    const float4* __restrict__ packed, int M, int N, int B, int rsplit,
    int Qmax, float* __restrict__ part)
{
    const int zc    = blockIdx.z;
    const int dir   = zc / rsplit;
    const int chunk = zc - dir * rsplit;
    const int b     = blockIdx.y;

    const int Q = dir ? N : M;
    const int R = dir ? M : N;
    const size_t qbase = dir ? ((size_t)B*M + (size_t)b*N) : ((size_t)b*M);
    const size_t rbase = dir ? ((size_t)b*M)               : ((size_t)B*M + (size_t)b*N);

    const int tid = threadIdx.x;
    const int Qq  = (Q + 3) >> 2;
    const int j0  = blockIdx.x * 256 + tid;
    const int j1  = j0 + Qq, j2 = j0 + 2*Qq, j3 = j0 + 3*Qq;

    f32x2 Qx01 = {0,0}, Qy01 = {0,0}, Qz01 = {0,0};
    f32x2 Qx23 = {0,0}, Qy23 = {0,0}, Qz23 = {0,0};
    float qn0 = 0, qn1 = 0, qn2 = 0, qn3 = 0;
    if (j0 < Q) { float4 qp = packed[qbase+j0]; Qx01.x = -0.5f*qp.x; Qy01.x = -0.5f*qp.y; Qz01.x = -0.5f*qp.z; qn0 = qp.w; }
    if (j1 < Q) { float4 qp = packed[qbase+j1]; Qx01.y = -0.5f*qp.x; Qy01.y = -0.5f*qp.y; Qz01.y = -0.5f*qp.z; qn1 = qp.w; }
    if (j2 < Q) { float4 qp = packed[qbase+j2]; Qx23.x = -0.5f*qp.x; Qy23.x = -0.5f*qp.y; Qz23.x = -0.5f*qp.z; qn2 = qp.w; }
    if (j3 < Q) { float4 qp = packed[qbase+j3]; Qx23.y = -0.5f*qp.x; Qy23.y = -0.5f*qp.y; Qz23.y = -0.5f*qp.z; qn3 = qp.w; }

    __shared__ float4 sh[TPTS];
    const f32x2* sh2 = (const f32x2*)sh;

    const int chunkLen = (R + rsplit - 1) / rsplit;
    const int start = chunk * chunkLen;
    const int end   = min(R, start + chunkLen);

    float best0 = INFINITY, best1 = INFINITY, best2 = INFINITY, best3 = INFINITY;
    for (int t0 = start; t0 < end; t0 += TPTS) {
        const int tl = min(TPTS, end - t0);
        __syncthreads();
        for (int p = tid; p < tl; p += 256) sh[p] = packed[rbase + t0 + p];
        __syncthreads();

        int i = 0;
        for (; i + 8 <= tl; i += 8) {
            #pragma unroll
            for (int u = 0; u < 8; u += 2) {
                const f32x2 pa0 = sh2[2*(i+u)+0], pa1 = sh2[2*(i+u)+1];
                const f32x2 pb0 = sh2[2*(i+u)+2], pb1 = sh2[2*(i+u)+3];
                const f32x2 ta01 = pk_fma_bcast_lo(Qx01, pa0, pk_fma_bcast_hi(Qy01, pa0, pk_fma_zinit(Qz01, pa1)));
                const f32x2 ta23 = pk_fma_bcast_lo(Qx23, pa0, pk_fma_bcast_hi(Qy23, pa0, pk_fma_zinit(Qz23, pa1)));
                const f32x2 tb01 = pk_fma_bcast_lo(Qx01, pb0, pk_fma_bcast_hi(Qy01, pb0, pk_fma_zinit(Qz01, pb1)));
                const f32x2 tb23 = pk_fma_bcast_lo(Qx23, pb0, pk_fma_bcast_hi(Qy23, pb0, pk_fma_zinit(Qz23, pb1)));
                best0 = min3f(ta01.x, tb01.x, best0);
                best1 = min3f(ta01.y, tb01.y, best1);
                best2 = min3f(ta23.x, tb23.x, best2);
                best3 = min3f(ta23.y, tb23.y, best3);
            }
        }
        for (; i < tl; ++i) {
            const f32x2 p0 = sh2[2*i], p1 = sh2[2*i+1];
            const f32x2 t01 = pk_fma_bcast_lo(Qx01, p0, pk_fma_bcast_hi(Qy01, p0, pk_fma_zinit(Qz01, p1)));
            const f32x2 t23 = pk_fma_bcast_lo(Qx23, p0, pk_fma_bcast_hi(Qy23, p0, pk_fma_zinit(Qz23, p1)));
            best0 = fminf(best0, t01.x); best1 = fminf(best1, t01.y);
            best2 = fminf(best2, t23.x); best3 = fminf(best3, t23.y);
        }
    }

    const size_t base = (((size_t)dir * B + b) * rsplit + chunk) * (size_t)Qmax;
    if (j0 < Q) part[base + j0] = best0 + qn0;
    if (j1 < Q) part[base + j1] = best1 + qn1;
    if (j2 < Q) part[base + j2] = best2 + qn2;
    if (j3 < Q) part[base + j3] = best3 + qn3;
}

// Stage 2: combine rsplit partial mins, Huber, wave reduce, atomicAdd.
__global__ __launch_bounds__(256) void huber_reduce(
    const float* __restrict__ part, const int* __restrict__ cptr,
    int M, int N, int B, int rsplit, int Qmax, float* __restrict__ out)
{
    const int dir = blockIdx.z;
    const int b   = blockIdx.y;
    const int Q   = dir ? N : M;
    const int j   = blockIdx.x * blockDim.x + threadIdx.x;

    float h = 0.f;
    if (j < Q) {
        const size_t base = (((size_t)dir * B + b) * rsplit) * (size_t)Qmax + j;
        float v = part[base];
        #pragma unroll 4
        for (int k = 1; k < rsplit; ++k) v = fminf(v, part[base + (size_t)k * Qmax]);
        const float c = decode_scalar(cptr);
        h = (v < c) ? (0.5f * v * v) : (c * v - 0.5f * c * c);
    }

    #pragma unroll
    for (int off = 32; off > 0; off >>= 1) h += __shfl_down(h, off, 64);
    if ((threadIdx.x & 63) == 0) atomicAdd(out, h);
}

extern "C" void kernel_launch(void* const* d_in, const int* in_sizes, int n_in,
                              void* d_out, int out_size, void* d_ws, size_t ws_size,
                              hipStream_t stream) {
    const float* preds = (const float*)d_in[0];
    const float* gts   = (const float*)d_in[1];
    const int*   cptr  = (const int*)d_in[2];

    const int B = 4, D = 3;
    const int M = in_sizes[0] / (B * D);
    const int N = in_sizes[1] / (B * D);
    const int Qmax = (M > N) ? M : N;
    const int nP = B * M, nG = B * N;

    const size_t packedBytes = ((size_t)nP + (size_t)nG) * sizeof(float4);
    int rsplit = 16;
    while (rsplit > 1 &&
           packedBytes + 2ull * B * rsplit * (size_t)Qmax * sizeof(float) > ws_size)
        rsplit >>= 1;

    float4* packed = (float4*)d_ws;
    float*  part   = (float*)((char*)d_ws + packedBytes);
    float*  out    = (float*)d_out;

    hipMemsetAsync(d_out, 0, (size_t)out_size * sizeof(float), stream);

    dim3 g0((max(nP, nG) + 255) / 256, 2, 1);
    pack_pts<<<g0, 256, 0, stream>>>(preds, gts, nP, nG, packed);

    const int Qq = (Qmax + 3) / 4;
    dim3 g1((Qq + 255) / 256, B, 2 * rsplit);
    nn_partial_min<<<g1, 256, 0, stream>>>(packed, M, N, B, rsplit, Qmax, part);

    dim3 g2((Qmax + 255) / 256, B, 2);
    huber_reduce<<<g2, 256, 0, stream>>>(part, cptr, M, N, B, rsplit, Qmax, out);
}